// Round 1
// baseline (618.008 us; speedup 1.0000x reference)
//
#include <hip/hip_runtime.h>

static constexpr int BATCH  = 2048;
static constexpr int PL     = 64;      // players per batch item
static constexpr int NSEQ   = BATCH * PL;   // 131072 sequences
static constexpr int VOCABN = 10000;

__device__ __forceinline__ float fast_rcp(float x) { return __builtin_amdgcn_rcpf(x); }
__device__ __forceinline__ float sigm(float x) { return fast_rcp(1.f + __expf(-x)); }
__device__ __forceinline__ float tanh_f(float x) {
    // 1 - 2/(e^{2x}+1); saturates correctly at +-inf
    return 1.f - 2.f * fast_rcp(__expf(2.f * x) + 1.f);
}

// ---------------------------------------------------------------------------
// Kernel A: Zx_table[v][unit][gate] = b[col] + sum_d emb[v][d]*Wk[d][col],
// col = gate*32 + unit.  Gate-interleaved layout so the LSTM kernel can fetch
// its 4 gate pre-activations with ONE float4 load per lane.
// ---------------------------------------------------------------------------
__global__ __launch_bounds__(128) void build_zx(const float* __restrict__ emb,
                                                const float* __restrict__ Wk,
                                                const float* __restrict__ bias,
                                                float* __restrict__ table) {
    const int v = blockIdx.x;
    const int o = threadIdx.x;                 // column 0..127
    float acc = bias[o];
    const float* er = emb + v * 32;            // wave-uniform -> scalar loads
    #pragma unroll
    for (int d = 0; d < 32; ++d) acc = fmaf(er[d], Wk[d * 128 + o], acc);
    const int unit = o & 31, gate = o >> 5;
    table[v * 128 + unit * 4 + gate] = acc;
}

// ---------------------------------------------------------------------------
// Kernel B: bidirectional LSTM. 32 lanes per sequence, lane j owns hidden
// unit j. Wr fragments (128 f32/lane) pinned in VGPRs. h broadcast through a
// tiny double-buffered LDS staging area (1 ds_write + 8 uniform ds_read_b128
// per step). Masked steps select the old state (no divergence).
// ---------------------------------------------------------------------------
__global__ __launch_bounds__(256) void lstm_kernel(const int* __restrict__ x,
                                                   const float* __restrict__ Wr,
                                                   const float* __restrict__ table,
                                                   float* __restrict__ state) {
    __shared__ float hbuf[2][8][32];
    const int sub = threadIdx.x >> 5;          // half-wave (= sequence slot) 0..7
    const int j   = threadIdx.x & 31;          // hidden unit
    const int seq = blockIdx.x * 8 + sub;

    // Wr fragment: wr[k] = {Wr[k][j], Wr[k][32+j], Wr[k][64+j], Wr[k][96+j]}
    float4 wr[32];
    #pragma unroll
    for (int k = 0; k < 32; ++k) {
        wr[k].x = Wr[k * 128 +       j];
        wr[k].y = Wr[k * 128 + 32 +  j];
        wr[k].z = Wr[k * 128 + 64 +  j];
        wr[k].w = Wr[k * 128 + 96 +  j];
    }

    // all 16 tokens of this sequence
    int tk[16];
    {
        const int4* xv = (const int4*)(x + (long)seq * 16);
        #pragma unroll
        for (int t4 = 0; t4 < 4; ++t4) {
            int4 v = xv[t4];
            tk[t4 * 4 + 0] = v.x; tk[t4 * 4 + 1] = v.y;
            tk[t4 * 4 + 2] = v.z; tk[t4 * 4 + 3] = v.w;
        }
    }

    const float4* tb = (const float4*)table;   // [vocab][32] float4

    #pragma unroll
    for (int dir = 0; dir < 2; ++dir) {
        float h = 0.f, c = 0.f;
        #pragma unroll
        for (int s = 0; s < 16; ++s) {
            const int t   = dir ? (15 - s) : s;
            const int tok = tk[t];
            // gate pre-activations from the token table (i,f,g,o for unit j)
            float4 z = tb[tok * 32 + j];

            // broadcast h across the half-wave via LDS (double-buffered)
            const int pb = s & 1;
            hbuf[pb][sub][j] = h;
            asm volatile("s_waitcnt lgkmcnt(0)" ::: "memory");
            const float4* hb4 = (const float4*)hbuf[pb][sub];
            #pragma unroll
            for (int k4 = 0; k4 < 8; ++k4) {
                float4 hb = hb4[k4];
                z.x = fmaf(hb.x, wr[k4*4+0].x, z.x);
                z.y = fmaf(hb.x, wr[k4*4+0].y, z.y);
                z.z = fmaf(hb.x, wr[k4*4+0].z, z.z);
                z.w = fmaf(hb.x, wr[k4*4+0].w, z.w);
                z.x = fmaf(hb.y, wr[k4*4+1].x, z.x);
                z.y = fmaf(hb.y, wr[k4*4+1].y, z.y);
                z.z = fmaf(hb.y, wr[k4*4+1].z, z.z);
                z.w = fmaf(hb.y, wr[k4*4+1].w, z.w);
                z.x = fmaf(hb.z, wr[k4*4+2].x, z.x);
                z.y = fmaf(hb.z, wr[k4*4+2].y, z.y);
                z.z = fmaf(hb.z, wr[k4*4+2].z, z.z);
                z.w = fmaf(hb.z, wr[k4*4+2].w, z.w);
                z.x = fmaf(hb.w, wr[k4*4+3].x, z.x);
                z.y = fmaf(hb.w, wr[k4*4+3].y, z.y);
                z.z = fmaf(hb.w, wr[k4*4+3].z, z.z);
                z.w = fmaf(hb.w, wr[k4*4+3].w, z.w);
            }
            const float ig = sigm(z.x);
            const float fg = sigm(z.y);
            const float gg = tanh_f(z.z);
            const float og = sigm(z.w);
            const float cn = fmaf(fg, c, ig * gg);
            const float hn = og * tanh_f(cn);
            const bool m = (tok != 0);
            h = m ? hn : h;
            c = m ? cn : c;
        }
        state[(long)seq * 64 + dir * 32 + j] = h;
    }
}

// ---------------------------------------------------------------------------
// Kernel C: out[b][o] = tanh( sum_q state[b][q] * Wd[q][o] + bd[o] )
// 4 batch rows per block; 4 q-groups x 64 o-lanes; LDS partial reduce.
// ---------------------------------------------------------------------------
__global__ __launch_bounds__(256) void proj_kernel(const float* __restrict__ state,
                                                   const float* __restrict__ Wd,
                                                   const float* __restrict__ bd,
                                                   float* __restrict__ out) {
    __shared__ float red[4][4][64];
    const int o  = threadIdx.x & 63;
    const int qg = threadIdx.x >> 6;
    const int b0 = blockIdx.x * 4;
    float acc0 = 0.f, acc1 = 0.f, acc2 = 0.f, acc3 = 0.f;
    const float4* sv = (const float4*)state;
    #pragma unroll 2
    for (int qq = 0; qq < 256; ++qq) {
        const int q = qg * 1024 + qq * 4;
        const float w0 = Wd[(q + 0) * 64 + o];
        const float w1 = Wd[(q + 1) * 64 + o];
        const float w2 = Wd[(q + 2) * 64 + o];
        const float w3 = Wd[(q + 3) * 64 + o];
        const float4 s0 = sv[((b0 + 0) * 4096 + q) >> 2];
        const float4 s1 = sv[((b0 + 1) * 4096 + q) >> 2];
        const float4 s2 = sv[((b0 + 2) * 4096 + q) >> 2];
        const float4 s3 = sv[((b0 + 3) * 4096 + q) >> 2];
        acc0 = fmaf(s0.x, w0, fmaf(s0.y, w1, fmaf(s0.z, w2, fmaf(s0.w, w3, acc0))));
        acc1 = fmaf(s1.x, w0, fmaf(s1.y, w1, fmaf(s1.z, w2, fmaf(s1.w, w3, acc1))));
        acc2 = fmaf(s2.x, w0, fmaf(s2.y, w1, fmaf(s2.z, w2, fmaf(s2.w, w3, acc2))));
        acc3 = fmaf(s3.x, w0, fmaf(s3.y, w1, fmaf(s3.z, w2, fmaf(s3.w, w3, acc3))));
    }
    red[qg][0][o] = acc0;
    red[qg][1][o] = acc1;
    red[qg][2][o] = acc2;
    red[qg][3][o] = acc3;
    __syncthreads();
    const float r = red[0][qg][o] + red[1][qg][o] + red[2][qg][o] + red[3][qg][o] + bd[o];
    out[(b0 + qg) * 64 + o] = tanh_f(r);
}

extern "C" void kernel_launch(void* const* d_in, const int* in_sizes, int n_in,
                              void* d_out, int out_size, void* d_ws, size_t ws_size,
                              hipStream_t stream) {
    const int*   x    = (const int*)d_in[0];
    const float* emb  = (const float*)d_in[1];
    const float* Wk   = (const float*)d_in[2];
    const float* Wr   = (const float*)d_in[3];
    const float* bias = (const float*)d_in[4];
    const float* Wd   = (const float*)d_in[5];
    const float* bd   = (const float*)d_in[6];
    float* out = (float*)d_out;

    float* table = (float*)d_ws;                 // 10000*128 f32 = 5.12 MB
    float* state = table + VOCABN * 128;         // 131072*64 f32 = 33.5 MB

    build_zx<<<VOCABN, 128, 0, stream>>>(emb, Wk, bias, table);
    lstm_kernel<<<NSEQ / 8, 256, 0, stream>>>(x, Wr, table, state);
    proj_kernel<<<BATCH / 4, 256, 0, stream>>>(state, Wd, bd, out);
}

// Round 3
// 260.583 us; speedup vs baseline: 2.3716x; 2.3716x over previous
//
#include <hip/hip_runtime.h>

typedef _Float16 half8_t __attribute__((ext_vector_type(8)));
typedef __fp16   fp16x2_t __attribute__((ext_vector_type(2)));
typedef float    f32x4_t __attribute__((ext_vector_type(4)));

static constexpr int BATCH = 2048;
static constexpr int NSEQ  = BATCH * 64;   // 131072 sequences
static constexpr int VOCABN = 10000;
static constexpr float L2E = 1.44269504f;

__device__ __forceinline__ float sig2(float z, float bp) {
    float e = __builtin_amdgcn_exp2f(fmaf(z, -L2E, bp));
    return __builtin_amdgcn_rcpf(1.f + e);
}
__device__ __forceinline__ float th2(float z, float bp) {
    float e = __builtin_amdgcn_exp2f(fmaf(z, 2.f * L2E, bp));
    return fmaf(-2.f, __builtin_amdgcn_rcpf(1.f + e), 1.f);
}
__device__ __forceinline__ float tanh1(float z) {
    float e = __builtin_amdgcn_exp2f(z * (2.f * L2E));
    return fmaf(-2.f, __builtin_amdgcn_rcpf(1.f + e), 1.f);
}

__global__ __launch_bounds__(256) void conv_emb(const float* __restrict__ emb,
                                                _Float16* __restrict__ e16) {
    int i = blockIdx.x * 256 + threadIdx.x;
    if (i < VOCABN * 32) e16[i] = (_Float16)emb[i];
}

__global__ __launch_bounds__(128) void prep_frags(const float* __restrict__ Wr,
                                                  const float* __restrict__ Wk,
                                                  ushort* __restrict__ fwr,
                                                  ushort* __restrict__ fwk) {
    const int lane = threadIdx.x & 63;
    const bool isWk = threadIdx.x >= 64;
    const float* W = isWk ? Wk : Wr;
    ushort* dst = isWk ? fwk : fwr;
    #pragma unroll
    for (int b = 0; b < 8; ++b) {
        #pragma unroll
        for (int j = 0; j < 8; ++j) {
            int kk = (lane >> 4) * 8 + j;
            int krow = isWk ? kk : ((kk >> 1) + 16 * (kk & 1));
            int col = b * 16 + (lane & 15);
            _Float16 v = (_Float16)W[krow * 128 + col];
            dst[(b * 64 + lane) * 8 + j] = __builtin_bit_cast(ushort, v);
        }
    }
}

__global__ __launch_bounds__(256) void lstm_mfma(const int* __restrict__ x,
                                                 const ushort* __restrict__ fwr,
                                                 const ushort* __restrict__ fwk,
                                                 const float* __restrict__ bias,
                                                 const _Float16* __restrict__ e16,
                                                 float* __restrict__ state) {
    __shared__ int toks[16][64];
    __shared__ unsigned int hx[4][2][16 * 20];

    const int tid = threadIdx.x, lane = tid & 63, wid = tid >> 6;
    const int i15 = lane & 15, grp = lane >> 4;
    const long blkSeq = (long)blockIdx.x * 64;

    {
        int s = tid >> 2, t4 = (tid & 3) * 4;
        int4 v = *(const int4*)(x + (blkSeq + s) * 16 + t4);
        toks[t4 + 0][s] = v.x; toks[t4 + 1][s] = v.y;
        toks[t4 + 2][s] = v.z; toks[t4 + 3][s] = v.w;
    }

    const half8_t* fwr8 = (const half8_t*)fwr;
    const half8_t* fwk8 = (const half8_t*)fwk;
    half8_t Bwr[8], Bwk[8];
    #pragma unroll
    for (int b = 0; b < 8; ++b) { Bwr[b] = fwr8[b * 64 + lane]; Bwk[b] = fwk8[b * 64 + lane]; }

    float bp[8];
    #pragma unroll
    for (int b = 0; b < 8; ++b) {
        float bb = bias[b * 16 + i15];
        bp[b] = (b == 4 || b == 5) ? (2.f * L2E) * bb : (-L2E) * bb;
    }
    __syncthreads();

    const int wseq = wid * 16;
    const f32x4_t kzero = {0.f, 0.f, 0.f, 0.f};
    unsigned int* h0 = &hx[wid][0][0];
    unsigned int* h1 = &hx[wid][1][0];

    #pragma unroll 1
    for (int dir = 0; dir < 2; ++dir) {
        float hreg[4][2], creg[4][2];
        #pragma unroll
        for (int r = 0; r < 4; ++r) { hreg[r][0] = hreg[r][1] = creg[r][0] = creg[r][1] = 0.f; }

        half8_t eb0 = *(const half8_t*)(e16 + (long)toks[dir ? 15 : 0][wseq + i15] * 32 + grp * 8);
        half8_t eb1 = *(const half8_t*)(e16 + (long)toks[dir ? 14 : 1][wseq + i15] * 32 + grp * 8);

        #pragma unroll 2
        for (int s = 0; s < 16; ++s) {
            const int t = dir ? 15 - s : s;
            int mt0 = toks[t][wseq + grp * 4 + 0];
            int mt1 = toks[t][wseq + grp * 4 + 1];
            int mt2 = toks[t][wseq + grp * 4 + 2];
            int mt3 = toks[t][wseq + grp * 4 + 3];

            half8_t ecur = (s & 1) ? eb1 : eb0;
            f32x4_t acc[8];
            if (s == 0) {
                #pragma unroll
                for (int b = 0; b < 8; ++b)
                    acc[b] = __builtin_amdgcn_mfma_f32_16x16x32_f16(ecur, Bwk[b], kzero, 0, 0, 0);
            } else {
                const unsigned int* rb = (s & 1) ? h0 : h1;
                half8_t Ah = *(const half8_t*)(rb + i15 * 20 + grp * 4);
                #pragma unroll
                for (int b = 0; b < 8; ++b) {
                    f32x4_t tt = __builtin_amdgcn_mfma_f32_16x16x32_f16(Ah, Bwr[b], kzero, 0, 0, 0);
                    acc[b] = __builtin_amdgcn_mfma_f32_16x16x32_f16(ecur, Bwk[b], tt, 0, 0, 0);
                }
            }
            if (s < 14) {
                const int tn = dir ? 13 - s : s + 2;
                half8_t ld = *(const half8_t*)(e16 + (long)toks[tn][wseq + i15] * 32 + grp * 8);
                if (s & 1) eb1 = ld; else eb0 = ld;
            }

            unsigned int* wb = (s & 1) ? h1 : h0;
            int mts[4] = {mt0, mt1, mt2, mt3};
            #pragma unroll
            for (int r = 0; r < 4; ++r) {
                bool m = (mts[r] != 0);
                #pragma unroll
                for (int hf = 0; hf < 2; ++hf) {
                    float zi = acc[0 + hf][r], zf = acc[2 + hf][r];
                    float zg = acc[4 + hf][r], zo = acc[6 + hf][r];
                    float ii = sig2(zi, bp[0 + hf]);
                    float ff = sig2(zf, bp[2 + hf]);
                    float gg = th2(zg, bp[4 + hf]);
                    float oo = sig2(zo, bp[6 + hf]);
                    float cn = fmaf(ff, creg[r][hf], ii * gg);
                    float hn = oo * tanh1(cn);
                    creg[r][hf] = m ? cn : creg[r][hf];
                    hreg[r][hf] = m ? hn : hreg[r][hf];
                }
                fp16x2_t p2 = __builtin_amdgcn_cvt_pkrtz(hreg[r][0], hreg[r][1]);
                wb[(grp * 4 + r) * 20 + i15] = __builtin_bit_cast(unsigned int, p2);
            }
        }
        #pragma unroll
        for (int r = 0; r < 4; ++r)
            #pragma unroll
            for (int hf = 0; hf < 2; ++hf)
                state[(blkSeq + wseq + grp * 4 + r) * 64 + dir * 32 + hf * 16 + i15] = hreg[r][hf];
    }
}

__global__ __launch_bounds__(256) void proj_kernel(const float* __restrict__ state,
                                                   const float* __restrict__ Wd,
                                                   const float* __restrict__ bd,
                                                   float* __restrict__ out) {
    __shared__ float red[4][4][64];
    const int o  = threadIdx.x & 63;
    const int qg = threadIdx.x >> 6;
    const int b0 = blockIdx.x * 4;
    float acc0 = 0.f, acc1 = 0.f, acc2 = 0.f, acc3 = 0.f;
    const float4* sv = (const float4*)state;
    #pragma unroll 2
    for (int qq = 0; qq < 256; ++qq) {
        const int q = qg * 1024 + qq * 4;
        const float w0 = Wd[(q + 0) * 64 + o];
        const float w1 = Wd[(q + 1) * 64 + o];
        const float w2 = Wd[(q + 2) * 64 + o];
        const float w3 = Wd[(q + 3) * 64 + o];
        const float4 s0 = sv[((b0 + 0) * 4096 + q) >> 2];
        const float4 s1 = sv[((b0 + 1) * 4096 + q) >> 2];
        const float4 s2 = sv[((b0 + 2) * 4096 + q) >> 2];
        const float4 s3 = sv[((b0 + 3) * 4096 + q) >> 2];
        acc0 = fmaf(s0.x, w0, fmaf(s0.y, w1, fmaf(s0.z, w2, fmaf(s0.w, w3, acc0))));
        acc1 = fmaf(s1.x, w0, fmaf(s1.y, w1, fmaf(s1.z, w2, fmaf(s1.w, w3, acc1))));
        acc2 = fmaf(s2.x, w0, fmaf(s2.y, w1, fmaf(s2.z, w2, fmaf(s2.w, w3, acc2))));
        acc3 = fmaf(s3.x, w0, fmaf(s3.y, w1, fmaf(s3.z, w2, fmaf(s3.w, w3, acc3))));
    }
    red[qg][0][o] = acc0;
    red[qg][1][o] = acc1;
    red[qg][2][o] = acc2;
    red[qg][3][o] = acc3;
    __syncthreads();
    const float r = red[0][qg][o] + red[1][qg][o] + red[2][qg][o] + red[3][qg][o] + bd[o];
    out[(b0 + qg) * 64 + o] = tanh1(r);
}

extern "C" void kernel_launch(void* const* d_in, const int* in_sizes, int n_in,
                              void* d_out, int out_size, void* d_ws, size_t ws_size,
                              hipStream_t stream) {
    const int*   x    = (const int*)d_in[0];
    const float* emb  = (const float*)d_in[1];
    const float* Wk   = (const float*)d_in[2];
    const float* Wr   = (const float*)d_in[3];
    const float* bias = (const float*)d_in[4];
    const float* Wd   = (const float*)d_in[5];
    const float* bd   = (const float*)d_in[6];
    float* out = (float*)d_out;

    float*    state = (float*)d_ws;
    _Float16* e16   = (_Float16*)((char*)d_ws + 33554432);
    ushort*   fwr   = (ushort*)((char*)d_ws + 34194432);
    ushort*   fwk   = fwr + 4096;

    conv_emb<<<(VOCABN * 32 + 255) / 256, 256, 0, stream>>>(emb, e16);
    prep_frags<<<1, 128, 0, stream>>>(Wr, Wk, fwr, fwk);
    lstm_mfma<<<NSEQ / 64, 256, 0, stream>>>(x, fwr, fwk, bias, e16, state);
    proj_kernel<<<BATCH / 4, 256, 0, stream>>>(state, Wd, bd, out);
}